// Round 6
// baseline (225.993 us; speedup 1.0000x reference)
//
#include <hip/hip_runtime.h>
#include <math.h>

#define BATCH 4096
#define NFEAT 4
#define VOCAB 100000
#define EMB 64
#define D_IN 256
#define D_H 256
#define D_O 128
#define XS_STRIDE 264      // ushort stride (+8 pad)
#define YS_STRIDE 132      // float stride

typedef __attribute__((ext_vector_type(8))) short bf16x8;
typedef __attribute__((ext_vector_type(4))) float f32x4;

__device__ inline ushort f2bf(float f) {
  union { float f; unsigned u; } v; v.f = f;
  unsigned u = v.u;
  return (ushort)((u + 0x7fffu + ((u >> 16) & 1u)) >> 16);  // RNE
}

// bf16 B-fragment (8 consecutive k at fixed n) from fp32 row-major W[k][n].
__device__ inline bf16x8 load_wfrag(const float* __restrict__ wp, int strideN) {
  bf16x8 b;
#pragma unroll
  for (int j = 0; j < 8; j++) b[j] = (short)f2bf(wp[(size_t)j * strideN]);
  return b;
}

// ---------------------------------------------------------------------------
// Single fused kernel, no grid sync. Block b (256 blocks, 512 thr = 8 waves):
//   user rows [16b,16b+16)  -> tile 0
//   item rows [16b,16b+19)  -> tile 1 (rows 0-15) + halo tile 2 (rows 16-18,
//                              rows 19-31 zero-padded; 3-row redundancy vs
//                              block b+1 makes the score band self-contained)
// Phases: gather -> L1 (48 col-tasks) -> L2 (24 col-tasks) -> row-norm (35
// rows, in place) -> banded scores out[i][j] = un_i . vn_{(i+j)%B} - log(sw).
// MFMA 16x16x32 frags: A: lane m=lane&15 holds A[m][quad*8+j];
// B: lane n=lane&15 holds B[quad*8+j][n]; C/D: D[quad*4+reg][lane&15].
// ---------------------------------------------------------------------------
__global__ __launch_bounds__(512) void fused_kernel(
    const int* __restrict__ user_ids, const int* __restrict__ item_ids,
    const int* __restrict__ sw_ids,
    const float* __restrict__ user_tables, const float* __restrict__ item_tables,
    const float* __restrict__ sw_table,
    const float* __restrict__ uW1, const float* __restrict__ ub1,
    const float* __restrict__ uW2, const float* __restrict__ ub2,
    const float* __restrict__ iW1, const float* __restrict__ ib1,
    const float* __restrict__ iW2, const float* __restrict__ ib2,
    float* __restrict__ out) {
  const int r0 = blockIdx.x * 16;
  const int tid = threadIdx.x;
  const int lane = tid & 63;
  const int w = tid >> 6;

  __shared__ ushort Xs_u[16][XS_STRIDE];
  __shared__ ushort Xs_i[32][XS_STRIDE];
  __shared__ ushort Hs_u[16][XS_STRIDE];
  __shared__ ushort Hs_i[32][XS_STRIDE];
  __shared__ float Ys_u[16][YS_STRIDE];
  __shared__ float Ys_i[32][YS_STRIDE];

  // ---- gather + bf16 convert: user 16x64 + item 19x64 float4 slots ----
  for (int s = tid; s < 2240; s += 512) {
    bool isu = s < 1024;
    int t = isu ? s : s - 1024;
    int row = t >> 6;
    int c4 = t & 63;
    int f = c4 >> 4;
    int grow = (r0 + row) & (BATCH - 1);  // item halo may wrap; user never does
    const int* ids = isu ? user_ids : item_ids;
    const float* tab = isu ? user_tables : item_tables;
    int id = ids[(size_t)grow * NFEAT + f];
    float4 v = ((const float4*)(tab + ((size_t)f * VOCAB + (size_t)id) * EMB))[c4 & 15];
    ushort4 o = {f2bf(v.x), f2bf(v.y), f2bf(v.z), f2bf(v.w)};
    if (isu) *(ushort4*)&Xs_u[row][c4 * 4] = o;
    else     *(ushort4*)&Xs_i[row][c4 * 4] = o;
  }
  // zero halo pad rows 19..31 of Xs_i (66 ushort4 per padded row)
  for (int z = tid; z < 13 * 66; z += 512) {
    int row = 19 + z / 66, c = z % 66;
    ushort4 zz = {0, 0, 0, 0};
    *(ushort4*)&Xs_i[row][c * 4] = zz;
  }
  __syncthreads();

  const int m = lane & 15;
  const int quad = lane >> 4;

  // ---- layer 1: 3 tiles x 16 col-groups = 48 tasks, 6 per wave ----
#pragma unroll
  for (int s = 0; s < 6; s++) {
    int t = w * 6 + s;
    int tile = t >> 4;     // 0 user, 1 item, 2 item-halo
    int ct = t & 15;
    const ushort (*X)[XS_STRIDE] = tile == 0 ? Xs_u : (tile == 1 ? Xs_i : Xs_i + 16);
    ushort (*H)[XS_STRIDE] = tile == 0 ? Hs_u : (tile == 1 ? Hs_i : Hs_i + 16);
    const float* Wm = tile == 0 ? uW1 : iW1;
    const float* bm = tile == 0 ? ub1 : ib1;
    bf16x8 a[8];
#pragma unroll
    for (int k0 = 0; k0 < 8; k0++)
      a[k0] = *(const bf16x8*)&X[m][k0 * 32 + quad * 8];
    int n = ct * 16 + m;
    const float* wp = Wm + (size_t)(quad * 8) * D_H + n;
    f32x4 acc = {0.f, 0.f, 0.f, 0.f};
#pragma unroll
    for (int k0 = 0; k0 < 8; k0++)
      acc = __builtin_amdgcn_mfma_f32_16x16x32_bf16(
          a[k0], load_wfrag(wp + (size_t)k0 * 32 * D_H, D_H), acc, 0, 0, 0);
    float bias = bm[n];
#pragma unroll
    for (int reg = 0; reg < 4; reg++)
      H[quad * 4 + reg][n] = f2bf(fmaxf(acc[reg] + bias, 0.f));
  }
  __syncthreads();

  // ---- layer 2: 3 tiles x 8 col-groups = 24 tasks, 3 per wave ----
#pragma unroll
  for (int s = 0; s < 3; s++) {
    int t = w * 3 + s;
    int tile = t >> 3;
    int ct = t & 7;
    const ushort (*H)[XS_STRIDE] = tile == 0 ? Hs_u : (tile == 1 ? Hs_i : Hs_i + 16);
    float (*Y)[YS_STRIDE] = tile == 0 ? Ys_u : (tile == 1 ? Ys_i : Ys_i + 16);
    const float* Wm = tile == 0 ? uW2 : iW2;
    const float* bm = tile == 0 ? ub2 : ib2;
    bf16x8 h[8];
#pragma unroll
    for (int k0 = 0; k0 < 8; k0++)
      h[k0] = *(const bf16x8*)&H[m][k0 * 32 + quad * 8];
    int n = ct * 16 + m;
    const float* wp = Wm + (size_t)(quad * 8) * D_O + n;
    f32x4 acc = {0.f, 0.f, 0.f, 0.f};
#pragma unroll
    for (int k0 = 0; k0 < 8; k0++)
      acc = __builtin_amdgcn_mfma_f32_16x16x32_bf16(
          h[k0], load_wfrag(wp + (size_t)k0 * 32 * D_O, D_O), acc, 0, 0, 0);
    float bias = bm[n];
#pragma unroll
    for (int reg = 0; reg < 4; reg++)
      Y[quad * 4 + reg][n] = fmaxf(acc[reg] + bias, 0.f);
  }
  __syncthreads();

  // ---- row L2-normalize in place: 35 rows (16 user + 19 item) ----
#pragma unroll
  for (int rr = 0; rr < 5; rr++) {
    int row = rr * 8 + w;
    if (row < 35) {
      float* Y = row < 16 ? &Ys_u[row][0] : &Ys_i[row - 16][0];
      float y0 = Y[lane];
      float y1 = Y[64 + lane];
      float s2 = y0 * y0 + y1 * y1;
#pragma unroll
      for (int off = 32; off; off >>= 1) s2 += __shfl_xor(s2, off);
      float inv = 1.f / fmaxf(sqrtf(s2), 1e-8f);
      Y[lane] = y0 * inv;
      Y[64 + lane] = y1 * inv;
    }
  }
  __syncthreads();

  // ---- banded scores: 16 rows x 4 cols, 2 rows per wave ----
#pragma unroll
  for (int rr = 0; rr < 2; rr++) {
    int il = w * 2 + rr;          // local row 0..15
    int i = r0 + il;
    float u0 = Ys_u[il][lane];
    float u1 = Ys_u[il][64 + lane];
#pragma unroll
    for (int j = 0; j < 4; j++) {
      int cl = il + j;            // local item row 0..18
      float v0 = Ys_i[cl][lane];
      float v1 = Ys_i[cl][64 + lane];
      float d = u0 * v0 + u1 * v1;
#pragma unroll
      for (int off = 32; off; off >>= 1) d += __shfl_xor(d, off);
      if (lane == 0) {
        int c = (i + j) & (BATCH - 1);
        out[(size_t)i * 4 + j] = d - logf(sw_table[sw_ids[c]]);
      }
    }
  }
}

extern "C" void kernel_launch(void* const* d_in, const int* in_sizes, int n_in,
                              void* d_out, int out_size, void* d_ws, size_t ws_size,
                              hipStream_t stream) {
  (void)in_sizes; (void)n_in; (void)out_size; (void)d_ws; (void)ws_size;
  const int*   user_ids    = (const int*)d_in[0];
  const int*   item_ids    = (const int*)d_in[1];
  const int*   sw_ids      = (const int*)d_in[2];
  const float* user_tables = (const float*)d_in[3];
  const float* item_tables = (const float*)d_in[4];
  const float* sw_table    = (const float*)d_in[5];
  const float* uW1 = (const float*)d_in[6];
  const float* ub1 = (const float*)d_in[7];
  const float* uW2 = (const float*)d_in[8];
  const float* ub2 = (const float*)d_in[9];
  const float* iW1 = (const float*)d_in[10];
  const float* ib1 = (const float*)d_in[11];
  const float* iW2 = (const float*)d_in[12];
  const float* ib2 = (const float*)d_in[13];
  float* out = (float*)d_out;

  fused_kernel<<<BATCH / 16, 512, 0, stream>>>(
      user_ids, item_ids, sw_ids, user_tables, item_tables, sw_table,
      uW1, ub1, uW2, ub2, iW1, ib1, iW2, ib2, out);
}

// Round 7
// 223.933 us; speedup vs baseline: 1.0092x; 1.0092x over previous
//
#include <hip/hip_runtime.h>
#include <math.h>

#define BATCH 4096
#define NFEAT 4
#define VOCAB 100000
#define EMB 64
#define D_IN 256
#define D_H 256
#define D_O 128
#define XS_STRIDE 264      // ushort stride (+8 pad)
#define YS_STRIDE 132      // float stride

typedef __attribute__((ext_vector_type(8))) short bf16x8;
typedef __attribute__((ext_vector_type(4))) float f32x4;

__device__ inline ushort f2bf(float f) {
  union { float f; unsigned u; } v; v.f = f;
  unsigned u = v.u;
  return (ushort)((u + 0x7fffu + ((u >> 16) & 1u)) >> 16);  // RNE
}

// ---------------------------------------------------------------------------
// Prep: transpose + convert weights to bf16 Wt[n][k] (R3's proven cheap path:
// makes tower B-fragments single 16B loads).
// ---------------------------------------------------------------------------
__global__ __launch_bounds__(256) void prep_kernel(
    const float* __restrict__ uW1, const float* __restrict__ uW2,
    const float* __restrict__ iW1, const float* __restrict__ iW2,
    ushort* __restrict__ W1tu, ushort* __restrict__ W2tu,
    ushort* __restrict__ W1ti, ushort* __restrict__ W2ti) {
  int idx = blockIdx.x * 256 + threadIdx.x;  // 0 .. 196608
  if (idx < 65536) {
    int n = idx >> 8, k = idx & 255;
    W1tu[idx] = f2bf(uW1[k * 256 + n]);
  } else if (idx < 131072) {
    int j = idx - 65536; int n = j >> 8, k = j & 255;
    W1ti[j] = f2bf(iW1[k * 256 + n]);
  } else if (idx < 163840) {
    int j = idx - 131072; int n = j >> 8, k = j & 255;
    W2tu[j] = f2bf(uW2[k * 128 + n]);
  } else {
    int j = idx - 163840; int n = j >> 8, k = j & 255;
    W2ti[j] = f2bf(iW2[k * 128 + n]);
  }
}

// ---------------------------------------------------------------------------
// Fused tower+score, one block = 16 user rows + 19 item rows (3-row halo,
// rows 19..31 zero-padded third MFMA tile). 512 thr (8 waves), 256 blocks.
// Weights pre-transposed bf16 -> B-fragment = one 16B load.
// MFMA 16x16x32 frags: A lane m=lane&15 holds A[m][quad*8+j];
// B lane n=lane&15 holds B[quad*8+j][n]; C/D: D[quad*4+reg][lane&15].
// ---------------------------------------------------------------------------
__global__ __launch_bounds__(512) void fused_kernel(
    const int* __restrict__ user_ids, const int* __restrict__ item_ids,
    const int* __restrict__ sw_ids,
    const float* __restrict__ user_tables, const float* __restrict__ item_tables,
    const float* __restrict__ sw_table,
    const ushort* __restrict__ W1tu, const float* __restrict__ ub1,
    const ushort* __restrict__ W2tu, const float* __restrict__ ub2,
    const ushort* __restrict__ W1ti, const float* __restrict__ ib1,
    const ushort* __restrict__ W2ti, const float* __restrict__ ib2,
    float* __restrict__ out) {
  const int r0 = blockIdx.x * 16;
  const int tid = threadIdx.x;
  const int lane = tid & 63;
  const int w = tid >> 6;

  __shared__ ushort Xs_u[16][XS_STRIDE];
  __shared__ ushort Xs_i[32][XS_STRIDE];
  __shared__ ushort Hs_u[16][XS_STRIDE];
  __shared__ ushort Hs_i[32][XS_STRIDE];
  __shared__ float Ys_u[16][YS_STRIDE];
  __shared__ float Ys_i[32][YS_STRIDE];

  // ---- gather + bf16 convert: user 16x64 + item 19x64 float4 slots ----
  for (int s = tid; s < 2240; s += 512) {
    bool isu = s < 1024;
    int t = isu ? s : s - 1024;
    int row = t >> 6;
    int c4 = t & 63;
    int f = c4 >> 4;
    int grow = (r0 + row) & (BATCH - 1);  // item halo may wrap
    const int* ids = isu ? user_ids : item_ids;
    const float* tab = isu ? user_tables : item_tables;
    int id = ids[(size_t)grow * NFEAT + f];
    float4 v = ((const float4*)(tab + ((size_t)f * VOCAB + (size_t)id) * EMB))[c4 & 15];
    ushort4 o = {f2bf(v.x), f2bf(v.y), f2bf(v.z), f2bf(v.w)};
    if (isu) *(ushort4*)&Xs_u[row][c4 * 4] = o;
    else     *(ushort4*)&Xs_i[row][c4 * 4] = o;
  }
  // zero halo pad rows 19..31 of Xs_i
  for (int z = tid; z < 13 * 66; z += 512) {
    int row = 19 + z / 66, c = z % 66;
    ushort4 zz = {0, 0, 0, 0};
    *(ushort4*)&Xs_i[row][c * 4] = zz;
  }
  __syncthreads();

  const int m = lane & 15;
  const int quad = lane >> 4;

  // ---- layer 1: 3 tiles x 16 col-groups = 48 tasks, 6 per wave ----
#pragma unroll
  for (int s = 0; s < 6; s++) {
    int t = w * 6 + s;
    int tile = t >> 4;     // 0 user, 1 item, 2 item-halo
    int ct = t & 15;
    const ushort (*X)[XS_STRIDE] = tile == 0 ? Xs_u : (tile == 1 ? Xs_i : Xs_i + 16);
    ushort (*H)[XS_STRIDE] = tile == 0 ? Hs_u : (tile == 1 ? Hs_i : Hs_i + 16);
    const ushort* Wt = tile == 0 ? W1tu : W1ti;
    const float* bm = tile == 0 ? ub1 : ib1;
    bf16x8 a[8];
#pragma unroll
    for (int k0 = 0; k0 < 8; k0++)
      a[k0] = *(const bf16x8*)&X[m][k0 * 32 + quad * 8];
    int n = ct * 16 + m;
    const ushort* wp = Wt + (size_t)n * 256 + quad * 8;
    f32x4 acc = {0.f, 0.f, 0.f, 0.f};
#pragma unroll
    for (int k0 = 0; k0 < 8; k0++)
      acc = __builtin_amdgcn_mfma_f32_16x16x32_bf16(
          a[k0], *(const bf16x8*)(wp + k0 * 32), acc, 0, 0, 0);
    float bias = bm[n];
#pragma unroll
    for (int reg = 0; reg < 4; reg++)
      H[quad * 4 + reg][n] = f2bf(fmaxf(acc[reg] + bias, 0.f));
  }
  __syncthreads();

  // ---- layer 2: 3 tiles x 8 col-groups = 24 tasks, 3 per wave ----
#pragma unroll
  for (int s = 0; s < 3; s++) {
    int t = w * 3 + s;
    int tile = t >> 3;
    int ct = t & 7;
    const ushort (*H)[XS_STRIDE] = tile == 0 ? Hs_u : (tile == 1 ? Hs_i : Hs_i + 16);
    float (*Y)[YS_STRIDE] = tile == 0 ? Ys_u : (tile == 1 ? Ys_i : Ys_i + 16);
    const ushort* Wt = tile == 0 ? W2tu : W2ti;
    const float* bm = tile == 0 ? ub2 : ib2;
    bf16x8 h[8];
#pragma unroll
    for (int k0 = 0; k0 < 8; k0++)
      h[k0] = *(const bf16x8*)&H[m][k0 * 32 + quad * 8];
    int n = ct * 16 + m;
    const ushort* wp = Wt + (size_t)n * 256 + quad * 8;
    f32x4 acc = {0.f, 0.f, 0.f, 0.f};
#pragma unroll
    for (int k0 = 0; k0 < 8; k0++)
      acc = __builtin_amdgcn_mfma_f32_16x16x32_bf16(
          h[k0], *(const bf16x8*)(wp + k0 * 32), acc, 0, 0, 0);
    float bias = bm[n];
#pragma unroll
    for (int reg = 0; reg < 4; reg++)
      Y[quad * 4 + reg][n] = fmaxf(acc[reg] + bias, 0.f);
  }
  __syncthreads();

  // ---- row L2-normalize in place: 35 rows (16 user + 19 item) ----
#pragma unroll
  for (int rr = 0; rr < 5; rr++) {
    int row = rr * 8 + w;
    if (row < 35) {
      float* Y = row < 16 ? &Ys_u[row][0] : &Ys_i[row - 16][0];
      float y0 = Y[lane];
      float y1 = Y[64 + lane];
      float s2 = y0 * y0 + y1 * y1;
#pragma unroll
      for (int off = 32; off; off >>= 1) s2 += __shfl_xor(s2, off);
      float inv = 1.f / fmaxf(sqrtf(s2), 1e-8f);
      Y[lane] = y0 * inv;
      Y[64 + lane] = y1 * inv;
    }
  }
  __syncthreads();

  // ---- banded scores: 16 rows x 4 cols, 2 rows per wave ----
#pragma unroll
  for (int rr = 0; rr < 2; rr++) {
    int il = w * 2 + rr;          // local user row 0..15
    int i = r0 + il;
    float u0 = Ys_u[il][lane];
    float u1 = Ys_u[il][64 + lane];
#pragma unroll
    for (int j = 0; j < 4; j++) {
      int cl = il + j;            // local item row 0..18
      float v0 = Ys_i[cl][lane];
      float v1 = Ys_i[cl][64 + lane];
      float d = u0 * v0 + u1 * v1;
#pragma unroll
      for (int off = 32; off; off >>= 1) d += __shfl_xor(d, off);
      if (lane == 0) {
        int c = (i + j) & (BATCH - 1);
        out[(size_t)i * 4 + j] = d - logf(sw_table[sw_ids[c]]);
      }
    }
  }
}

extern "C" void kernel_launch(void* const* d_in, const int* in_sizes, int n_in,
                              void* d_out, int out_size, void* d_ws, size_t ws_size,
                              hipStream_t stream) {
  (void)in_sizes; (void)n_in; (void)out_size; (void)ws_size;
  const int*   user_ids    = (const int*)d_in[0];
  const int*   item_ids    = (const int*)d_in[1];
  const int*   sw_ids      = (const int*)d_in[2];
  const float* user_tables = (const float*)d_in[3];
  const float* item_tables = (const float*)d_in[4];
  const float* sw_table    = (const float*)d_in[5];
  const float* uW1 = (const float*)d_in[6];
  const float* ub1 = (const float*)d_in[7];
  const float* uW2 = (const float*)d_in[8];
  const float* ub2 = (const float*)d_in[9];
  const float* iW1 = (const float*)d_in[10];
  const float* ib1 = (const float*)d_in[11];
  const float* iW2 = (const float*)d_in[12];
  const float* ib2 = (const float*)d_in[13];
  float* out = (float*)d_out;

  // ws: bf16 transposed weights
  ushort* W1tu = (ushort*)d_ws;          // [256][256]
  ushort* W1ti = W1tu + 256 * 256;       // [256][256]
  ushort* W2tu = W1ti + 256 * 256;       // [128][256]
  ushort* W2ti = W2tu + 128 * 256;       // [128][256]

  prep_kernel<<<768, 256, 0, stream>>>(uW1, uW2, iW1, iW2, W1tu, W2tu, W1ti, W2ti);

  fused_kernel<<<BATCH / 16, 512, 0, stream>>>(
      user_ids, item_ids, sw_ids, user_tables, item_tables, sw_table,
      W1tu, ub1, W2tu, ub2, W1ti, ib1, W2ti, ib2, out);
}